// Round 2
// baseline (666.194 us; speedup 1.0000x reference)
//
#include <hip/hip_runtime.h>
#include <hip/hip_bf16.h>

#define N_NODES 100000
#define N_EDGES 1600000
#define D_FEAT 50
#define ALPHA 0.1f

// ---------------- fallback (atomic) path ----------------
__global__ void init_out_kernel(const float* __restrict__ h,
                                float* __restrict__ out, int n) {
    int idx = blockIdx.x * blockDim.x + threadIdx.x;
    if (idx < n) out[idx] = ALPHA * h[idx];
}

__global__ void scatter_atomic_kernel(const float* __restrict__ x,
                                      const float* __restrict__ vals,
                                      const int* __restrict__ rows,
                                      const int* __restrict__ cols,
                                      float* __restrict__ out) {
    long long idx = (long long)blockIdx.x * blockDim.x + threadIdx.x;
    long long total = (long long)N_EDGES * D_FEAT;
    if (idx >= total) return;
    int e = (int)(idx / D_FEAT);
    int d = (int)(idx % D_FEAT);
    float contrib = (1.0f - ALPHA) * vals[e] * x[(long long)cols[e] * D_FEAT + d];
    atomicAdd(&out[(long long)rows[e] * D_FEAT + d], contrib);
}

// ---------------- CSR-build path ----------------

__global__ void zero_counts_kernel(int* __restrict__ counts, int n) {
    int i = blockIdx.x * blockDim.x + threadIdx.x;
    if (i < n) counts[i] = 0;
}

__global__ void hist_kernel(const int* __restrict__ rows, int* __restrict__ counts) {
    int e = blockIdx.x * blockDim.x + threadIdx.x;
    if (e < N_EDGES) atomicAdd(&counts[rows[e]], 1);
}

// Single-block exclusive scan of counts[0..N) -> row_start[0..N], cursor copy.
__global__ void scan_kernel(const int* __restrict__ counts,
                            int* __restrict__ row_start,
                            int* __restrict__ cursor) {
    __shared__ int sums[1024];
    int t = threadIdx.x;
    const int ITEMS = (N_NODES + 1023) / 1024;  // 98
    int begin = t * ITEMS;
    int end = begin + ITEMS;
    if (end > N_NODES) end = N_NODES;
    if (begin > N_NODES) begin = N_NODES;
    int s = 0;
    for (int i = begin; i < end; ++i) s += counts[i];
    sums[t] = s;
    __syncthreads();
    // Hillis-Steele inclusive scan
    for (int off = 1; off < 1024; off <<= 1) {
        int v = (t >= off) ? sums[t - off] : 0;
        __syncthreads();
        sums[t] += v;
        __syncthreads();
    }
    int run = sums[t] - s;  // exclusive prefix of this thread's chunk
    for (int i = begin; i < end; ++i) {
        row_start[i] = run;
        cursor[i] = run;
        run += counts[i];
    }
    if (t == 1023) row_start[N_NODES] = run;  // == N_EDGES
}

__global__ void bucket_kernel(const float* __restrict__ vals,
                              const int* __restrict__ rows,
                              const int* __restrict__ cols,
                              int* __restrict__ cursor,
                              float* __restrict__ sval,
                              int* __restrict__ scol) {
    int e = blockIdx.x * blockDim.x + threadIdx.x;
    if (e >= N_EDGES) return;
    int r = rows[e];
    int pos = atomicAdd(&cursor[r], 1);
    sval[pos] = vals[e];
    scol[pos] = cols[e];
}

// One wave (64 lanes) per row; lane d accumulates feature d in a register.
__global__ void spmm_kernel(const float* __restrict__ x,
                            const float* __restrict__ h,
                            const int* __restrict__ row_start,
                            const float* __restrict__ sval,
                            const int* __restrict__ scol,
                            float* __restrict__ out) {
    int wave = (blockIdx.x * blockDim.x + threadIdx.x) >> 6;
    int lane = threadIdx.x & 63;
    if (wave >= N_NODES) return;
    int s = row_start[wave];
    int e_end = row_start[wave + 1];
    float acc = 0.0f;
    for (int e = s; e < e_end; ++e) {
        int c = scol[e];
        float v = sval[e];
        if (lane < D_FEAT) acc += v * x[c * D_FEAT + lane];
    }
    if (lane < D_FEAT) {
        int o = wave * D_FEAT + lane;
        out[o] = (1.0f - ALPHA) * acc + ALPHA * h[o];
    }
}

extern "C" void kernel_launch(void* const* d_in, const int* in_sizes, int n_in,
                              void* d_out, int out_size, void* d_ws, size_t ws_size,
                              hipStream_t stream) {
    const float* x        = (const float*)d_in[0];
    const float* h        = (const float*)d_in[1];
    const float* adj_vals = (const float*)d_in[2];
    const int*   adj_rows = (const int*)d_in[3];
    const int*   adj_cols = (const int*)d_in[4];
    float* out = (float*)d_out;

    // workspace layout (all 4-byte types)
    size_t needed = (size_t)(3 * N_NODES + 1 + 2 * N_EDGES) * 4;
    if (ws_size < needed) {
        // fallback: atomic scatter (round-1 kernel)
        int n_out = N_NODES * D_FEAT;
        init_out_kernel<<<(n_out + 255) / 256, 256, 0, stream>>>(h, out, n_out);
        long long total = (long long)N_EDGES * D_FEAT;
        scatter_atomic_kernel<<<(int)((total + 255) / 256), 256, 0, stream>>>(
            x, adj_vals, adj_rows, adj_cols, out);
        return;
    }

    int* counts    = (int*)d_ws;             // N
    int* row_start = counts + N_NODES;       // N+1
    int* cursor    = row_start + N_NODES + 1;// N
    float* sval    = (float*)(cursor + N_NODES);  // E
    int* scol      = (int*)(sval + N_EDGES);      // E

    zero_counts_kernel<<<(N_NODES + 255) / 256, 256, 0, stream>>>(counts, N_NODES);
    hist_kernel<<<(N_EDGES + 255) / 256, 256, 0, stream>>>(adj_rows, counts);
    scan_kernel<<<1, 1024, 0, stream>>>(counts, row_start, cursor);
    bucket_kernel<<<(N_EDGES + 255) / 256, 256, 0, stream>>>(
        adj_vals, adj_rows, adj_cols, cursor, sval, scol);
    spmm_kernel<<<(N_NODES * 64 + 255) / 256, 256, 0, stream>>>(
        x, h, row_start, sval, scol, out);
}

// Round 3
// 358.604 us; speedup vs baseline: 1.8577x; 1.8577x over previous
//
#include <hip/hip_runtime.h>
#include <hip/hip_bf16.h>

#define N_NODES 100000
#define N_EDGES 1600000
#define D_FEAT 50
#define ALPHA 0.1f
#define NB 391  // ceil(N_NODES/256)

// ---------------- fallback (atomic) path ----------------
__global__ void init_out_kernel(const float* __restrict__ h,
                                float* __restrict__ out, int n) {
    int idx = blockIdx.x * blockDim.x + threadIdx.x;
    if (idx < n) out[idx] = ALPHA * h[idx];
}

__global__ void scatter_atomic_kernel(const float* __restrict__ x,
                                      const float* __restrict__ vals,
                                      const int* __restrict__ rows,
                                      const int* __restrict__ cols,
                                      float* __restrict__ out) {
    long long idx = (long long)blockIdx.x * blockDim.x + threadIdx.x;
    long long total = (long long)N_EDGES * D_FEAT;
    if (idx >= total) return;
    int e = (int)(idx / D_FEAT);
    int d = (int)(idx % D_FEAT);
    float contrib = (1.0f - ALPHA) * vals[e] * x[(long long)cols[e] * D_FEAT + d];
    atomicAdd(&out[(long long)rows[e] * D_FEAT + d], contrib);
}

// ---------------- CSR-build path ----------------

__global__ void hist_kernel(const int* __restrict__ rows, int* __restrict__ counts) {
    int i = blockIdx.x * blockDim.x + threadIdx.x;
    int e = i * 4;
    if (e + 3 < N_EDGES) {
        int4 r = *(const int4*)(rows + e);
        atomicAdd(&counts[r.x], 1);
        atomicAdd(&counts[r.y], 1);
        atomicAdd(&counts[r.z], 1);
        atomicAdd(&counts[r.w], 1);
    } else {
        for (; e < N_EDGES; ++e) atomicAdd(&counts[rows[e]], 1);
    }
}

__global__ void block_sum_kernel(const int* __restrict__ counts, int* __restrict__ bsum) {
    __shared__ int sh[256];
    int t = threadIdx.x;
    int gi = blockIdx.x * 256 + t;
    sh[t] = (gi < N_NODES) ? counts[gi] : 0;
    __syncthreads();
    for (int off = 128; off > 0; off >>= 1) {
        if (t < off) sh[t] += sh[t + off];
        __syncthreads();
    }
    if (t == 0) bsum[blockIdx.x] = sh[0];
}

__global__ void scan_partials_kernel(const int* __restrict__ bsum,
                                     int* __restrict__ boff,
                                     int* __restrict__ row_start) {
    __shared__ int sh[512];
    int t = threadIdx.x;
    int v = (t < NB) ? bsum[t] : 0;
    sh[t] = v;
    __syncthreads();
    for (int off = 1; off < 512; off <<= 1) {
        int u = (t >= off) ? sh[t - off] : 0;
        __syncthreads();
        sh[t] += u;
        __syncthreads();
    }
    if (t < NB) boff[t] = sh[t] - v;          // exclusive prefix of block sums
    if (t == 0) row_start[N_NODES] = N_EDGES; // total
}

__global__ void scan_final_kernel(const int* __restrict__ counts,
                                  const int* __restrict__ boff,
                                  int* __restrict__ row_start,
                                  int* __restrict__ cursor) {
    __shared__ int sh[256];
    int t = threadIdx.x;
    int gi = blockIdx.x * 256 + t;
    int c = (gi < N_NODES) ? counts[gi] : 0;
    sh[t] = c;
    __syncthreads();
    for (int off = 1; off < 256; off <<= 1) {
        int u = (t >= off) ? sh[t - off] : 0;
        __syncthreads();
        sh[t] += u;
        __syncthreads();
    }
    if (gi < N_NODES) {
        int ex = sh[t] - c + boff[blockIdx.x];
        row_start[gi] = ex;
        cursor[gi] = ex;
    }
}

// Scatter each edge into its row bucket; pack (col, 0.9*val) as one float2.
__global__ void bucket_kernel(const float* __restrict__ vals,
                              const int* __restrict__ rows,
                              const int* __restrict__ cols,
                              int* __restrict__ cursor,
                              float2* __restrict__ packed) {
    int e = blockIdx.x * blockDim.x + threadIdx.x;
    if (e >= N_EDGES) return;
    int r = rows[e];
    int pos = atomicAdd(&cursor[r], 1);
    float2 p;
    p.x = __int_as_float(cols[e]);
    p.y = vals[e] * (1.0f - ALPHA);
    packed[pos] = p;
}

// One wave per row. Lane i loads edge (base+i) once per 64-edge chunk, then
// shuffle-broadcasts (col,val); lanes 0..49 accumulate their feature.
__global__ __launch_bounds__(256) void spmm_kernel(
        const float* __restrict__ x,
        const float* __restrict__ h,
        const int* __restrict__ row_start,
        const float2* __restrict__ packed,
        float* __restrict__ out) {
    int wid = (blockIdx.x * blockDim.x + threadIdx.x) >> 6;
    int lane = threadIdx.x & 63;
    if (wid >= N_NODES) return;
    int s = row_start[wid];
    int end = row_start[wid + 1];
    float acc0 = 0.0f, acc1 = 0.0f;
    for (int base = s; base < end; base += 64) {
        int n = end - base;
        if (n > 64) n = 64;
        float2 ev = make_float2(0.0f, 0.0f);
        if (lane < n) ev = packed[base + lane];
        int i = 0;
        for (; i + 1 < n; i += 2) {
            int   c0 = __shfl(__float_as_int(ev.x), i);
            float v0 = __shfl(ev.y, i);
            int   c1 = __shfl(__float_as_int(ev.x), i + 1);
            float v1 = __shfl(ev.y, i + 1);
            if (lane < D_FEAT) {
                acc0 += v0 * x[c0 * D_FEAT + lane];
                acc1 += v1 * x[c1 * D_FEAT + lane];
            }
        }
        if (i < n) {
            int   c = __shfl(__float_as_int(ev.x), i);
            float v = __shfl(ev.y, i);
            if (lane < D_FEAT) acc0 += v * x[c * D_FEAT + lane];
        }
    }
    if (lane < D_FEAT) {
        int o = wid * D_FEAT + lane;
        out[o] = (acc0 + acc1) + ALPHA * h[o];  // vals pre-scaled by (1-ALPHA)
    }
}

extern "C" void kernel_launch(void* const* d_in, const int* in_sizes, int n_in,
                              void* d_out, int out_size, void* d_ws, size_t ws_size,
                              hipStream_t stream) {
    const float* x        = (const float*)d_in[0];
    const float* h        = (const float*)d_in[1];
    const float* adj_vals = (const float*)d_in[2];
    const int*   adj_rows = (const int*)d_in[3];
    const int*   adj_cols = (const int*)d_in[4];
    float* out = (float*)d_out;

    // workspace layout (ints then float2 packed edges; pad to 8B alignment)
    // counts N | row_start N+1 | cursor N | bsum NB | boff NB | pad | packed E*2
    size_t n_ints = (size_t)N_NODES * 3 + 1 + 2 * NB;
    n_ints = (n_ints + 1) & ~(size_t)1;  // 8B align for float2
    size_t needed = n_ints * 4 + (size_t)N_EDGES * 8;

    if (ws_size < needed) {
        int n_out = N_NODES * D_FEAT;
        init_out_kernel<<<(n_out + 255) / 256, 256, 0, stream>>>(h, out, n_out);
        long long total = (long long)N_EDGES * D_FEAT;
        scatter_atomic_kernel<<<(int)((total + 255) / 256), 256, 0, stream>>>(
            x, adj_vals, adj_rows, adj_cols, out);
        return;
    }

    int* counts    = (int*)d_ws;                 // N
    int* row_start = counts + N_NODES;           // N+1
    int* cursor    = row_start + N_NODES + 1;    // N
    int* bsum      = cursor + N_NODES;           // NB
    int* boff      = bsum + NB;                  // NB
    float2* packed = (float2*)((int*)d_ws + n_ints);  // E

    hipMemsetAsync(counts, 0, (size_t)N_NODES * 4, stream);
    hist_kernel<<<(N_EDGES / 4 + 255) / 256, 256, 0, stream>>>(adj_rows, counts);
    block_sum_kernel<<<NB, 256, 0, stream>>>(counts, bsum);
    scan_partials_kernel<<<1, 512, 0, stream>>>(bsum, boff, row_start);
    scan_final_kernel<<<NB, 256, 0, stream>>>(counts, boff, row_start, cursor);
    bucket_kernel<<<(N_EDGES + 255) / 256, 256, 0, stream>>>(
        adj_vals, adj_rows, adj_cols, cursor, packed);
    spmm_kernel<<<(N_NODES * 64 + 255) / 256, 256, 0, stream>>>(
        x, h, row_start, packed, out);
}